// Round 5
// baseline (112.306 us; speedup 1.0000x reference)
//
#include <hip/hip_runtime.h>
#include <hip/hip_bf16.h>

#define B_    64
#define S_    513
#define T_    512
#define H_    1024
#define OUT_  128
#define NKT   32          // K-steps of BK=32
#define OWN   64          // owned rows per block
#define ROWS  96          // owned + margin
#define LGS   132         // logits LDS row stride (floats)

typedef __attribute__((ext_vector_type(8))) short short8_t;
typedef __attribute__((ext_vector_type(4))) float f32x4;

__device__ inline ushort f2bf(float f) {
    union { float f; unsigned u; } x; x.f = f;
    unsigned r = x.u + 0x7fffu + ((x.u >> 16) & 1u);   // RNE
    return (ushort)(r >> 16);
}

// 8 fp32 -> 8 bf16 via HW pack-convert (RNE), 4 VALU ops
__device__ inline short8_t cvt8(const float4& x, const float4& y) {
    union { int i[4]; short8_t s; } u;
    asm("v_cvt_pk_bf16_f32 %0, %1, %2" : "=v"(u.i[0]) : "v"(x.x), "v"(x.y));
    asm("v_cvt_pk_bf16_f32 %0, %1, %2" : "=v"(u.i[1]) : "v"(x.z), "v"(x.w));
    asm("v_cvt_pk_bf16_f32 %0, %1, %2" : "=v"(u.i[2]) : "v"(y.x), "v"(y.y));
    asm("v_cvt_pk_bf16_f32 %0, %1, %2" : "=v"(u.i[3]) : "v"(y.z), "v"(y.w));
    return u.s;
}

// ---------------------------------------------------------------------------
// Kernel 0: Wt[o][k] = bf16(W[k][o])  (256 KB, stays L2-resident)
// ---------------------------------------------------------------------------
__global__ __launch_bounds__(256) void wt_kernel(
    const float* __restrict__ W, ushort* __restrict__ Wt)
{
    __shared__ ushort tile[64][65];
    int k0 = blockIdx.x * 64, o0 = blockIdx.y * 64;
    int tid = threadIdx.x;
#pragma unroll
    for (int p = 0; p < 16; ++p) {
        int idx = tid + p * 256;
        int r = idx >> 6, c = idx & 63;
        tile[r][c] = f2bf(W[(size_t)(k0 + r) * OUT_ + o0 + c]);
    }
    __syncthreads();
#pragma unroll
    for (int p = 0; p < 16; ++p) {
        int idx = tid + p * 256;
        int c = idx >> 6, r = idx & 63;
        Wt[(size_t)(o0 + c) * H_ + k0 + r] = tile[r][c];
    }
}

// ---------------------------------------------------------------------------
// Fused: seg-info + register-direct bf16 MFMA GEMM (no LDS, no barriers in
// the K-loop) + segment-mean + bias + transposed store.
// Block = (batch, 64-row tile) + <=32-row margin, ext-clamped loads.
// 512 thr = 8 waves (2M x 4N), wave tile 48x32 (3x2 frags).
// grid 512 = 2 blocks/CU = 16 waves/CU.
// ---------------------------------------------------------------------------
__global__ __launch_bounds__(512, 4) void fused_kernel(
    const float* __restrict__ hs, const ushort* __restrict__ Wt,
    const float* __restrict__ bias, const int* __restrict__ seg,
    float* __restrict__ out)
{
    __shared__ float lg[ROWS * LGS];   // 50.7 KB epilogue logits tile
    __shared__ int sseg[ROWS];
    __shared__ int lstart[OWN];
    __shared__ int lcnt[OWN];
    __shared__ int sExt, sSlo;

    int bid  = blockIdx.x;
    int b    = bid >> 3;
    int tile = bid & 7;
    int t0   = tile * OWN;
    int Tl   = (T_ - t0) < ROWS ? (T_ - t0) : ROWS;   // 96, 64 on last tile

    int tid  = threadIdx.x;
    int lane = tid & 63;
    int w    = tid >> 6;
    int wm   = w & 1, wn = w >> 1;        // 2M x 4N
    int l15  = lane & 15, ksl = lane >> 4;

    // ---- segment info -----------------------------------------------------
    if (tid < Tl)  sseg[tid] = seg[b * T_ + t0 + tid];
    if (tid < OWN) { lstart[tid] = ROWS; lcnt[tid] = 0; }
    if (tid == 0)  sExt = Tl;
    __syncthreads();
    if (tid == 0) {
        bool start0 = (t0 == 0) || (seg[b * T_ + t0 - 1] != sseg[0]);
        sSlo = sseg[0] + (start0 ? 0 : 1);
    }
    if (tid >= OWN && tid < Tl && sseg[tid] != sseg[tid - 1])
        atomicMin(&sExt, tid);            // first segment start past OWN
    __syncthreads();
    int ext  = sExt;                      // rows [0, ext) are needed
    int s_lo = sSlo;
    int s_hi = sseg[OWN - 1] + 1;
    if (tid < ext) {
        int sid = sseg[tid];
        if (sid >= s_lo) {
            atomicMin(&lstart[sid - s_lo], tid);
            atomicAdd(&lcnt[sid - s_lo], 1);
        }
    }
    // (lstart/lcnt ordered by the pre-epilogue barrier)

    // ---- per-lane fragment base pointers (rows >= ext clamped to row 0) ---
    const float* ap[3];
#pragma unroll
    for (int fm = 0; fm < 3; ++fm) {
        int row = wm * 48 + fm * 16 + l15;
        int re  = row < ext ? row : 0;
        ap[fm] = hs + ((size_t)(b * S_ + 1 + t0 + re)) * H_ + ksl * 8;
    }
    const ushort* bp[2];
#pragma unroll
    for (int fn = 0; fn < 2; ++fn)
        bp[fn] = Wt + (size_t)(wn * 32 + fn * 16 + l15) * H_ + ksl * 8;

    f32x4 acc[3][2];
#pragma unroll
    for (int fm = 0; fm < 3; ++fm)
#pragma unroll
        for (int fn = 0; fn < 2; ++fn) acc[fm][fn] = (f32x4){0.f, 0.f, 0.f, 0.f};

    float4 xA[3][2], xB[3][2];
    int4   yA[2],   yB[2];

    auto LA = [&](float4 (&x)[3][2], int kt) {
#pragma unroll
        for (int fm = 0; fm < 3; ++fm) {
            const float* p = ap[fm] + kt * 32;
            x[fm][0] = *reinterpret_cast<const float4*>(p);
            x[fm][1] = *reinterpret_cast<const float4*>(p + 4);
        }
    };
    auto LB = [&](int4 (&y)[2], int kt) {
#pragma unroll
        for (int fn = 0; fn < 2; ++fn)
            y[fn] = *reinterpret_cast<const int4*>(bp[fn] + kt * 32);
    };
    auto STEP = [&](float4 (&x)[3][2], int4 (&y)[2]) {
        short8_t af[3], bf[2];
#pragma unroll
        for (int fm = 0; fm < 3; ++fm) af[fm] = cvt8(x[fm][0], x[fm][1]);
#pragma unroll
        for (int fn = 0; fn < 2; ++fn)
            bf[fn] = *reinterpret_cast<short8_t*>(&y[fn]);
#pragma unroll
        for (int fm = 0; fm < 3; ++fm)
#pragma unroll
            for (int fn = 0; fn < 2; ++fn)
                acc[fm][fn] = __builtin_amdgcn_mfma_f32_16x16x32_bf16(
                    af[fm], bf[fn], acc[fm][fn], 0, 0, 0);
    };

    // ---- K loop: register double-buffer, no LDS, no barriers --------------
    LA(xA, 0); LB(yA, 0);
    for (int kt = 0; kt < NKT; kt += 2) {
        LA(xB, kt + 1); LB(yB, kt + 1);
        STEP(xA, yA);
        if (kt + 2 < NKT) { LA(xA, kt + 2); LB(yA, kt + 2); }
        STEP(xB, yB);
    }

    // ---- epilogue: acc -> lg[t][o] ----------------------------------------
#pragma unroll
    for (int fm = 0; fm < 3; ++fm) {
        int rbase = wm * 48 + fm * 16 + ksl * 4;
#pragma unroll
        for (int fn = 0; fn < 2; ++fn) {
            int o = wn * 32 + fn * 16 + l15;
#pragma unroll
            for (int r = 0; r < 4; ++r)
                lg[(rbase + r) * LGS + o] = acc[fm][fn][r];
        }
    }
    __syncthreads();

    // ---- segment means + bias + transposed store --------------------------
    int sl   = tid & 63;
    int ogrp = tid >> 6;                  // 0..7
    int ns   = s_hi - s_lo;
    if (sl < ns) {
        int st = lstart[sl];
        int cn = lcnt[sl];
        float inv = 1.0f / (float)cn;
        float* dst = out + (size_t)b * OUT_ * T_ + s_lo + sl;
#pragma unroll 4
        for (int oi = 0; oi < 16; ++oi) {
            int o = ogrp + oi * 8;
            float sum = 0.f;
            for (int i = 0; i < cn; ++i) sum += lg[(st + i) * LGS + o];
            dst[(size_t)o * T_] = sum * inv + bias[o];
        }
    }

    // last tile zero-fills empty segment columns [s_hi, 512)
    if (tile == 7) {
        for (int o = ogrp; o < OUT_; o += 8)
            for (int s = s_hi + sl; s < T_; s += 64)
                out[((size_t)b * OUT_ + o) * T_ + s] = 0.f;
    }
}

// ---------------------------------------------------------------------------
extern "C" void kernel_launch(void* const* d_in, const int* in_sizes, int n_in,
                              void* d_out, int out_size, void* d_ws, size_t ws_size,
                              hipStream_t stream) {
    const float* hs   = (const float*)d_in[0];   // (B, S, H)
    const float* W    = (const float*)d_in[1];   // (H, OUT)
    const float* bias = (const float*)d_in[2];   // (OUT,)
    const int*   seg  = (const int*)d_in[3];     // (B, T)
    float* out = (float*)d_out;                  // (B, OUT, T)

    ushort* Wt = (ushort*)d_ws;                  // 256 KB

    wt_kernel<<<dim3(H_ / 64, OUT_ / 64), 256, 0, stream>>>(W, Wt);
    fused_kernel<<<B_ * (T_ / OWN), 512, 0, stream>>>(hs, Wt, bias, seg, out);
}

// Round 6
// 67.208 us; speedup vs baseline: 1.6710x; 1.6710x over previous
//
#include <hip/hip_runtime.h>
#include <hip/hip_bf16.h>

#define B_    64
#define S_    513
#define T_    512
#define H_    1024
#define OUT_  128
#define OWN   64          // owned positions per block
#define ROWS  96          // owned + margin
#define HP    512         // H elements per pass
#define NKK   16          // K-steps (of 32) per pass

typedef __attribute__((ext_vector_type(8))) short short8_t;
typedef __attribute__((ext_vector_type(4))) float f32x4;

__device__ inline ushort f2bf(float f) {
    union { float f; unsigned u; } x; x.f = f;
    unsigned r = x.u + 0x7fffu + ((x.u >> 16) & 1u);   // RNE
    return (ushort)(r >> 16);
}

// ---------------------------------------------------------------------------
// Kernel 0: Wt[o][k] = bf16(W[k][o])  (256 KB, stays L2-resident)
// ---------------------------------------------------------------------------
__global__ __launch_bounds__(256) void wt_kernel(
    const float* __restrict__ W, ushort* __restrict__ Wt)
{
    __shared__ ushort tile[64][65];
    int k0 = blockIdx.x * 64, o0 = blockIdx.y * 64;
    int tid = threadIdx.x;
#pragma unroll
    for (int p = 0; p < 16; ++p) {
        int idx = tid + p * 256;
        int r = idx >> 6, c = idx & 63;
        tile[r][c] = f2bf(W[(size_t)(k0 + r) * OUT_ + o0 + c]);
    }
    __syncthreads();
#pragma unroll
    for (int p = 0; p < 16; ++p) {
        int idx = tid + p * 256;
        int c = idx >> 6, r = idx & 63;
        Wt[(size_t)(o0 + c) * H_ + k0 + r] = tile[r][c];
    }
}

// ---------------------------------------------------------------------------
// Fused: stream x -> per-segment register sums -> LDS (bf16) -> tiny MFMA
// GEMM (64 segs x 128 out x 1024 K) -> /cnt + bias -> transposed store.
// Block = (batch, 64-position tile) + <=32-row margin. 512 thr = 8 waves
// (2M x 4N), wave tile 32x32 (2x2 frags). 2 H-passes, sums LDS 64 KB,
// 2 blocks/CU. Phase-1 loads: thread owns one H-column elem; every
// t-iteration is one fully-coalesced 2 KB row read, 8-deep pipelined.
// ---------------------------------------------------------------------------
__global__ __launch_bounds__(512, 4) void fused_kernel(
    const float* __restrict__ hs, const ushort* __restrict__ Wt,
    const float* __restrict__ bias, const int* __restrict__ seg,
    float* __restrict__ out)
{
    __shared__ ushort sums[32768];   // 64 KB: elem = unit*512 + seg*8 + e
    __shared__ int sseg[ROWS];
    __shared__ int lcnt[OWN];
    __shared__ int sExt, sSlo;

    int bid  = blockIdx.x;
    int b    = bid >> 3;
    int tile = bid & 7;
    int t0   = tile * OWN;
    int Tl   = (T_ - t0) < ROWS ? (T_ - t0) : ROWS;   // 96, 64 on last tile

    int tid  = threadIdx.x;
    int lane = tid & 63;
    int w    = tid >> 6;
    int wm   = w & 1, wn = w >> 1;        // 2M x 4N
    int l15  = lane & 15, ksl = lane >> 4;

    // ---- segment info -----------------------------------------------------
    if (tid < Tl)  sseg[tid] = seg[b * T_ + t0 + tid];
    if (tid < OWN) lcnt[tid] = 0;
    if (tid == 0)  sExt = Tl;
    __syncthreads();
    if (tid == 0) {
        bool start0 = (t0 == 0) || (seg[b * T_ + t0 - 1] != sseg[0]);
        sSlo = sseg[0] + (start0 ? 0 : 1);
    }
    if (tid >= OWN && tid < Tl && sseg[tid] != sseg[tid - 1])
        atomicMin(&sExt, tid);            // first segment start past OWN
    __syncthreads();
    int ext  = sExt;                      // rows [0, ext) needed
    int s_lo = sSlo;
    int s_hi = sseg[OWN - 1] + 1;
    int ns   = s_hi - s_lo;               // <= 64
    if (tid < ext) {
        int sid = sseg[tid] - s_lo;
        if (sid >= 0) atomicAdd(&lcnt[sid], 1);
    }
    __syncthreads();

    // ---- layout constants --------------------------------------------------
    const float* xcol = hs + ((size_t)(b * S_ + 1 + t0)) * H_ + tid;
    const ushort* bp0 = Wt + (size_t)(wn * 32 + l15) * H_ + ksl * 8;
    const ushort* bp1 = bp0 + (size_t)16 * H_;
    int widx   = ((tid >> 3) << 9) + (tid & 7);         // flush elem base
    int rbase0 = ksl * 512 + (wm * 32 + l15) * 8;       // fm=0 read base
    int rbase1 = rbase0 + 16 * 8;                       // fm=1

    f32x4 acc[2][2];
#pragma unroll
    for (int fm = 0; fm < 2; ++fm)
#pragma unroll
        for (int fn = 0; fn < 2; ++fn) acc[fm][fn] = (f32x4){0.f, 0.f, 0.f, 0.f};

    for (int pass = 0; pass < 2; ++pass) {
        // ================= phase 1: stream & segment-reduce ================
        const float* xp = xcol + pass * HP;
        int cur = -1; float racc = 0.f;
        float va[8], vc[8];

        auto LOADC = [&](float (&v)[8], int tb) {
#pragma unroll
            for (int i = 0; i < 8; ++i) {
                int t = tb + i; t = t < Tl ? t : Tl - 1;   // clamped (safe)
                v[i] = xp[(size_t)t * H_];
            }
        };
        auto PROC = [&](float (&v)[8], int tb) {
#pragma unroll
            for (int i = 0; i < 8; ++i) {
                int t = tb + i;
                if (t < ext) {
                    int sid = sseg[t] - s_lo;
                    if (sid >= 0) {
                        if (sid != cur) {
                            if (cur >= 0) sums[widx + (cur << 3)] = f2bf(racc);
                            cur = sid; racc = v[i];
                        } else {
                            racc += v[i];
                        }
                    }
                }
            }
        };

        LOADC(va, 0);
        for (int tb = 0; ; tb += 16) {
            LOADC(vc, tb + 8);
            PROC(va, tb);
            if (tb + 8 >= ext) break;
            LOADC(va, tb + 16);
            PROC(vc, tb + 8);
            if (tb + 16 >= ext) break;
        }
        if (cur >= 0) sums[widx + (cur << 3)] = f2bf(racc);
        __syncthreads();

        // ================= phase 2: MFMA GEMM on segment sums ==============
        const ushort* bq0 = bp0 + pass * HP;
        const ushort* bq1 = bp1 + pass * HP;
        short8_t bfA[2], bfB[2];

        auto LB2 = [&](short8_t (&d)[2], int kk) {
            d[0] = *reinterpret_cast<const short8_t*>(bq0 + kk * 32);
            d[1] = *reinterpret_cast<const short8_t*>(bq1 + kk * 32);
        };
        auto STEP = [&](int kk, short8_t (&bf)[2]) {
            short8_t a0 = *reinterpret_cast<const short8_t*>(&sums[rbase0 + kk * 2048]);
            short8_t a1 = *reinterpret_cast<const short8_t*>(&sums[rbase1 + kk * 2048]);
            acc[0][0] = __builtin_amdgcn_mfma_f32_16x16x32_bf16(a0, bf[0], acc[0][0], 0, 0, 0);
            acc[0][1] = __builtin_amdgcn_mfma_f32_16x16x32_bf16(a0, bf[1], acc[0][1], 0, 0, 0);
            acc[1][0] = __builtin_amdgcn_mfma_f32_16x16x32_bf16(a1, bf[0], acc[1][0], 0, 0, 0);
            acc[1][1] = __builtin_amdgcn_mfma_f32_16x16x32_bf16(a1, bf[1], acc[1][1], 0, 0, 0);
        };

        LB2(bfA, 0);
        for (int kk = 0; kk < NKK; kk += 2) {
            LB2(bfB, kk + 1);
            STEP(kk, bfA);
            if (kk + 2 < NKK) LB2(bfA, kk + 2);
            STEP(kk + 1, bfB);
        }
        __syncthreads();   // before next pass overwrites sums
    }

    // ================= epilogue: /cnt + bias + transposed store ============
    int rowb = wm * 32 + ksl * 4;
    float invc[2][4];
#pragma unroll
    for (int fm = 0; fm < 2; ++fm)
#pragma unroll
        for (int r = 0; r < 4; ++r) {
            int row = rowb + fm * 16 + r;
            int cn  = (row < ns) ? lcnt[row] : 1;
            invc[fm][r] = 1.0f / (float)(cn > 0 ? cn : 1);
        }
    float bv0 = bias[wn * 32 + l15];
    float bv1 = bias[wn * 32 + 16 + l15];
#pragma unroll
    for (int fm = 0; fm < 2; ++fm) {
        int row0 = rowb + fm * 16;
#pragma unroll
        for (int fn = 0; fn < 2; ++fn) {
            int o = wn * 32 + fn * 16 + l15;
            float bv = fn ? bv1 : bv0;
            float* dst = out + ((size_t)b * OUT_ + o) * T_ + s_lo + row0;
#pragma unroll
            for (int r = 0; r < 4; ++r)
                if (row0 + r < ns) dst[r] = acc[fm][fn][r] * invc[fm][r] + bv;
        }
    }

    // last tile zero-fills empty segment columns [s_hi, 512)
    if (tile == 7) {
        int sl = tid & 63, og = tid >> 6;
        for (int o = og; o < OUT_; o += 8)
            for (int s = s_hi + sl; s < T_; s += 64)
                out[((size_t)b * OUT_ + o) * T_ + s] = 0.f;
    }
}

// ---------------------------------------------------------------------------
extern "C" void kernel_launch(void* const* d_in, const int* in_sizes, int n_in,
                              void* d_out, int out_size, void* d_ws, size_t ws_size,
                              hipStream_t stream) {
    const float* hs   = (const float*)d_in[0];   // (B, S, H)
    const float* W    = (const float*)d_in[1];   // (H, OUT)
    const float* bias = (const float*)d_in[2];   // (OUT,)
    const int*   seg  = (const int*)d_in[3];     // (B, T)
    float* out = (float*)d_out;                  // (B, OUT, T)

    ushort* Wt = (ushort*)d_ws;                  // 256 KB

    wt_kernel<<<dim3(H_ / 64, OUT_ / 64), 256, 0, stream>>>(W, Wt);
    fused_kernel<<<B_ * (T_ / OWN), 512, 0, stream>>>(hs, Wt, bias, seg, out);
}

// Round 7
// 63.344 us; speedup vs baseline: 1.7730x; 1.0610x over previous
//
#include <hip/hip_runtime.h>
#include <hip/hip_bf16.h>

#define B_    64
#define S_    513
#define T_    512
#define H_    1024
#define OUT_  128
#define OWN   64          // owned positions per block
#define ROWS  96          // owned + margin ceiling
#define GS    32          // t-split row between thread groups
#define NKK   32          // K-steps of 32

typedef __attribute__((ext_vector_type(8))) short short8_t;
typedef __attribute__((ext_vector_type(4))) float f32x4;

__device__ inline ushort f2bf(float f) {
    union { float f; unsigned u; } x; x.f = f;
    unsigned r = x.u + 0x7fffu + ((x.u >> 16) & 1u);   // RNE
    return (ushort)(r >> 16);
}
__device__ inline float bf2f(ushort u) {
    union { unsigned u; float f; } x; x.u = (unsigned)u << 16; return x.f;
}

// ---------------------------------------------------------------------------
// Kernel 0: Wt[o][k] = bf16(W[k][o])  (256 KB, stays L2-resident)
// ---------------------------------------------------------------------------
__global__ __launch_bounds__(256) void wt_kernel(
    const float* __restrict__ W, ushort* __restrict__ Wt)
{
    __shared__ ushort tile[64][65];
    int k0 = blockIdx.x * 64, o0 = blockIdx.y * 64;
    int tid = threadIdx.x;
#pragma unroll
    for (int p = 0; p < 16; ++p) {
        int idx = tid + p * 256;
        int r = idx >> 6, c = idx & 63;
        tile[r][c] = f2bf(W[(size_t)(k0 + r) * OUT_ + o0 + c]);
    }
    __syncthreads();
#pragma unroll
    for (int p = 0; p < 16; ++p) {
        int idx = tid + p * 256;
        int c = idx >> 6, r = idx & 63;
        Wt[(size_t)(o0 + c) * H_ + k0 + r] = tile[r][c];
    }
}

// ---------------------------------------------------------------------------
// Fused: stream x (float4, t-split 2 groups) -> per-segment register sums ->
// LDS bf16 (XOR-slotted) -> MFMA GEMM 64x128x1024 -> /cnt + bias -> store.
// 512 blocks x 512 threads, 1 block/CU (136 KB LDS), 8 waves = 1M x 8N.
// ---------------------------------------------------------------------------
__global__ __launch_bounds__(512) void fused_kernel(
    const float* __restrict__ hs, const ushort* __restrict__ Wt,
    const float* __restrict__ bias, const int* __restrict__ seg,
    float* __restrict__ out)
{
    __shared__ __align__(16) ushort sums[65536];   // 128 KB
    __shared__ __align__(16) float  bnd[H_];       // 4 KB boundary partials
    __shared__ __align__(16) int sseg[ROWS];
    __shared__ int lcnt[OWN];
    __shared__ int sExt, sSlo;

    int bid  = blockIdx.x;
    int b    = bid >> 3;
    int tile = bid & 7;
    int t0   = tile * OWN;
    int Tl   = (T_ - t0) < ROWS ? (T_ - t0) : ROWS;   // 96, 64 on last tile

    int tid  = threadIdx.x;
    int lane = tid & 63;
    int wn   = tid >> 6;                 // wave 0..7 owns o-range [wn*16,+16)
    int l15  = lane & 15, ksl = lane >> 4;

    // ---- segment info -----------------------------------------------------
    if (tid < Tl)  sseg[tid] = seg[b * T_ + t0 + tid];
    if (tid < OWN) lcnt[tid] = 0;
    if (tid == 0)  sExt = Tl;
    __syncthreads();
    if (tid == 0) {
        bool start0 = (t0 == 0) || (seg[b * T_ + t0 - 1] != sseg[0]);
        sSlo = sseg[0] + (start0 ? 0 : 1);
    }
    if (tid >= OWN && tid < Tl && sseg[tid] != sseg[tid - 1])
        atomicMin(&sExt, tid);           // first segment start past OWN
    __syncthreads();
    int ext  = sExt;                     // rows [0, ext) needed, ext in [64,96]
    int s_lo = sSlo;
    int s_hi = sseg[OWN - 1] + 1;
    int ns   = s_hi - s_lo;              // <= 64
    if (tid < ext) {
        int sid = sseg[tid] - s_lo;
        if (sid >= 0) atomicAdd(&lcnt[sid], 1);
    }
    // boundary segment continuing across the GS split (block-uniform)
    int bnd_sid = (sseg[GS] == sseg[GS - 1] && sseg[GS - 1] >= s_lo)
                    ? sseg[GS - 1] - s_lo : -1;

    // ---- phase 1: stream & segment-reduce (2 t-groups, float4 cols) -------
    int g    = tid >> 8;                 // group 0: rows [0,GS); 1: [GS,ext)
    int col0 = (tid & 255) * 4;
    int rb   = g * GS;
    int nt   = g ? (ext - GS) : GS;
    const float* xp = hs + ((size_t)(b * S_ + 1 + t0)) * H_ + col0;
    int unit = col0 >> 3, e = col0 & 7;

    float4 racc = {0.f, 0.f, 0.f, 0.f};
    int cur = -1;

    auto FLUSH = [&](int sid, const float4& r) {
        if (g == 1 && sid == bnd_sid) {
            *reinterpret_cast<float4*>(&bnd[col0]) = r;
        } else {
            union { ushort u[4]; uint2 v; } pk;
            pk.u[0] = f2bf(r.x); pk.u[1] = f2bf(r.y);
            pk.u[2] = f2bf(r.z); pk.u[3] = f2bf(r.w);
            int el = unit * 512 + (((sid ^ (unit & 7))) << 3) + e;
            *reinterpret_cast<uint2*>(&sums[el]) = pk.v;
        }
    };
    auto LOADC = [&](float4 (&v)[4], int tb) {
#pragma unroll
        for (int i = 0; i < 4; ++i) {
            int t = rb + tb + i; t = t < Tl ? t : Tl - 1;   // clamped
            v[i] = *reinterpret_cast<const float4*>(xp + (size_t)t * H_);
        }
    };
    auto PROC = [&](float4 (&v)[4], int tb) {
        int4 sd = *reinterpret_cast<const int4*>(&sseg[rb + tb]);
        int sdv[4] = {sd.x, sd.y, sd.z, sd.w};
#pragma unroll
        for (int i = 0; i < 4; ++i) {
            if (tb + i < nt) {
                int sid = sdv[i] - s_lo;
                if (sid >= 0) {
                    if (sid != cur) {
                        if (cur >= 0) FLUSH(cur, racc);
                        cur = sid; racc = v[i];
                    } else {
                        racc.x += v[i].x; racc.y += v[i].y;
                        racc.z += v[i].z; racc.w += v[i].w;
                    }
                }
            }
        }
    };

    float4 va[4], vc[4];
    LOADC(va, 0);
    for (int tb = 0;; tb += 8) {
        LOADC(vc, tb + 4);
        PROC(va, tb);
        if (tb + 4 >= nt) break;
        LOADC(va, tb + 8);
        PROC(vc, tb + 4);
        if (tb + 8 >= nt) break;
    }
    if (cur >= 0) FLUSH(cur, racc);
    __syncthreads();

    // boundary fixup: sums[bnd_sid] += bnd (bf16 rmw, 4 cols/thread)
    if (bnd_sid >= 0 && tid < 256) {
        int base = unit * 512 + (((bnd_sid ^ (unit & 7))) << 3) + e;
#pragma unroll
        for (int j = 0; j < 4; ++j)
            sums[base + j] = f2bf(bf2f(sums[base + j]) + bnd[col0 + j]);
    }
    __syncthreads();

    // ---- phase 2: MFMA GEMM on segment sums (A: LDS, B: L2-hot Wt) --------
    const ushort* bp = Wt + (size_t)(wn * 16 + l15) * H_ + ksl * 8;
    int aE = ksl * 512 + ((l15 ^ ksl) << 3);         // even kk: unit&7 = ksl
    int aO = ksl * 512 + ((l15 ^ (ksl + 4)) << 3);   // odd kk: unit&7 = ksl+4

    f32x4 acc[4];
#pragma unroll
    for (int fm = 0; fm < 4; ++fm) acc[fm] = (f32x4){0.f, 0.f, 0.f, 0.f};

    short8_t bfA, bfB;
    bfA = *reinterpret_cast<const short8_t*>(bp);
    for (int kk = 0; kk < NKK; kk += 2) {
        bfB = *reinterpret_cast<const short8_t*>(bp + (kk + 1) * 32);
#pragma unroll
        for (int fm = 0; fm < 4; ++fm) {
            short8_t a = *reinterpret_cast<const short8_t*>(
                &sums[aE + fm * 128 + kk * 2048]);
            acc[fm] = __builtin_amdgcn_mfma_f32_16x16x32_bf16(a, bfA, acc[fm], 0, 0, 0);
        }
        if (kk + 2 < NKK)
            bfA = *reinterpret_cast<const short8_t*>(bp + (kk + 2) * 32);
#pragma unroll
        for (int fm = 0; fm < 4; ++fm) {
            short8_t a = *reinterpret_cast<const short8_t*>(
                &sums[aO + fm * 128 + (kk + 1) * 2048]);
            acc[fm] = __builtin_amdgcn_mfma_f32_16x16x32_bf16(a, bfB, acc[fm], 0, 0, 0);
        }
    }

    // ---- epilogue: /cnt + bias + transposed store -------------------------
    {
        int o = wn * 16 + l15;
        float bv = bias[o];
        float* dstb = out + ((size_t)b * OUT_ + o) * T_ + s_lo;
#pragma unroll
        for (int fm = 0; fm < 4; ++fm) {
            int row0 = fm * 16 + ksl * 4;
#pragma unroll
            for (int r = 0; r < 4; ++r) {
                int row = row0 + r;
                if (row < ns)
                    dstb[row] = acc[fm][r] / (float)lcnt[row] + bv;
            }
        }
    }

    // last tile zero-fills empty segment columns [s_hi, 512)
    if (tile == 7) {
        int sl = tid & 63, og = tid >> 6;
        for (int o = og; o < OUT_; o += 8)
            for (int s = s_hi + sl; s < T_; s += 64)
                out[((size_t)b * OUT_ + o) * T_ + s] = 0.f;
    }
}

// ---------------------------------------------------------------------------
extern "C" void kernel_launch(void* const* d_in, const int* in_sizes, int n_in,
                              void* d_out, int out_size, void* d_ws, size_t ws_size,
                              hipStream_t stream) {
    const float* hs   = (const float*)d_in[0];   // (B, S, H)
    const float* W    = (const float*)d_in[1];   // (H, OUT)
    const float* bias = (const float*)d_in[2];   // (OUT,)
    const int*   seg  = (const int*)d_in[3];     // (B, T)
    float* out = (float*)d_out;                  // (B, OUT, T)

    ushort* Wt = (ushort*)d_ws;                  // 256 KB

    wt_kernel<<<dim3(H_ / 64, OUT_ / 64), 256, 0, stream>>>(W, Wt);
    fused_kernel<<<B_ * (T_ / OWN), 512, 0, stream>>>(hs, Wt, bias, seg, out);
}

// Round 8
// 57.359 us; speedup vs baseline: 1.9580x; 1.1043x over previous
//
#include <hip/hip_runtime.h>
#include <hip/hip_bf16.h>

#define B_    64
#define S_    513
#define T_    512
#define H_    1024
#define OUT_  128

#define BM 64
#define BN 128
#define BK 32
#define NKT (H_ / BK)   // 32

typedef __attribute__((ext_vector_type(8))) short short8_t;
typedef __attribute__((ext_vector_type(4))) float f32x4;

__device__ inline ushort f2bf(float f) {
    union { float f; unsigned u; } x; x.f = f;
    unsigned r = x.u + 0x7fffu + ((x.u >> 16) & 1u);   // RNE
    return (ushort)(r >> 16);
}
__device__ inline float bf2f(ushort u) {
    union { unsigned u; float f; } x; x.u = (unsigned)u << 16; return x.f;
}

// ---------------------------------------------------------------------------
// Kernel 0: Wt[o][k] = bf16(W[k][o])  (256 KB, stays L2-resident)
// ---------------------------------------------------------------------------
__global__ __launch_bounds__(256) void wt_kernel(
    const float* __restrict__ W, ushort* __restrict__ Wt)
{
    __shared__ ushort tile[64][65];
    int k0 = blockIdx.x * 64, o0 = blockIdx.y * 64;
    int tid = threadIdx.x;
#pragma unroll
    for (int p = 0; p < 16; ++p) {
        int idx = tid + p * 256;
        int r = idx >> 6, c = idx & 63;
        tile[r][c] = f2bf(W[(size_t)(k0 + r) * OUT_ + o0 + c]);
    }
    __syncthreads();
#pragma unroll
    for (int p = 0; p < 16; ++p) {
        int idx = tid + p * 256;
        int c = idx >> 6, r = idx & 63;
        Wt[(size_t)(o0 + c) * H_ + k0 + r] = tile[r][c];
    }
}

// ---------------------------------------------------------------------------
// Kernel 1: logits(bf16) = bf16(x) @ bf16(W) via MFMA 16x16x32 (no bias; raw
// xW stored). Round-2 proven body: 64x128 tile, BK=32, 256 thr = 4 waves
// (2x2), wave tile 32x64, XOR-swizzled LDS, double-buffered, 1 barrier/iter.
// 25.6 KB LDS -> 6 blocks/CU. grid 512.
// ---------------------------------------------------------------------------
__global__ __launch_bounds__(256) void gemm_kernel(
    const float* __restrict__ hs, const ushort* __restrict__ Wt,
    ushort* __restrict__ logits)
{
    __shared__ __align__(16) ushort As[2][BM * BK];
    __shared__ __align__(16) ushort Bs[2][BN * BK];

    int blk = blockIdx.x;
    int b   = blk >> 3;
    int t0  = (blk & 7) * BM;
    int tid = threadIdx.x;
    int lane = tid & 63;
    int wv = tid >> 6;
    int wm = wv & 1, wn = wv >> 1;
    int l15 = lane & 15, ksl = lane >> 4;

    int rowA = tid >> 2;          // 0..63
    int cblk = tid & 3;           // 16B chunk within BK
    int rowB1 = rowA + 64;

    const float*  aptr  = hs + ((size_t)(b * S_ + 1 + t0) + rowA) * H_ + cblk * 8;
    const ushort* bptr0 = Wt + (size_t)rowA  * H_ + cblk * 8;
    const ushort* bptr1 = Wt + (size_t)rowB1 * H_ + cblk * 8;

    auto swz = [](int row, int blkc) {
        return row * BK + ((blkc ^ ((row >> 1) & 3)) << 3);
    };
    int wAo  = swz(rowA, cblk);
    int wB0o = swz(rowA, cblk);
    int wB1o = swz(rowB1, cblk);

    int rAo[2], rBo[4];
#pragma unroll
    for (int fm = 0; fm < 2; ++fm) {
        int row = wm * 32 + fm * 16 + l15;
        rAo[fm] = swz(row, ksl);
    }
#pragma unroll
    for (int fn = 0; fn < 4; ++fn) {
        int row = wn * 64 + fn * 16 + l15;
        rBo[fn] = swz(row, ksl);
    }

    f32x4 acc[2][4];
#pragma unroll
    for (int fm = 0; fm < 2; ++fm)
#pragma unroll
        for (int fn = 0; fn < 4; ++fn) acc[fm][fn] = (f32x4){0.f, 0.f, 0.f, 0.f};

    float4 ra0, ra1;
    int4 rb0, rb1;

    auto loadT = [&](int kt) {
        const float* ap = aptr + kt * BK;
        ra0 = *reinterpret_cast<const float4*>(ap);
        ra1 = *reinterpret_cast<const float4*>(ap + 4);
        rb0 = *reinterpret_cast<const int4*>(bptr0 + kt * BK);
        rb1 = *reinterpret_cast<const int4*>(bptr1 + kt * BK);
    };
    auto writeT = [&](int nb) {
        union { ushort u[8]; int4 i; } pa;
        pa.u[0] = f2bf(ra0.x); pa.u[1] = f2bf(ra0.y);
        pa.u[2] = f2bf(ra0.z); pa.u[3] = f2bf(ra0.w);
        pa.u[4] = f2bf(ra1.x); pa.u[5] = f2bf(ra1.y);
        pa.u[6] = f2bf(ra1.z); pa.u[7] = f2bf(ra1.w);
        *reinterpret_cast<int4*>(&As[nb][wAo])  = pa.i;
        *reinterpret_cast<int4*>(&Bs[nb][wB0o]) = rb0;
        *reinterpret_cast<int4*>(&Bs[nb][wB1o]) = rb1;
    };
    auto computeT = [&](int cb) {
        short8_t af[2], bf[4];
#pragma unroll
        for (int fm = 0; fm < 2; ++fm)
            af[fm] = *reinterpret_cast<const short8_t*>(&As[cb][rAo[fm]]);
#pragma unroll
        for (int fn = 0; fn < 4; ++fn)
            bf[fn] = *reinterpret_cast<const short8_t*>(&Bs[cb][rBo[fn]]);
#pragma unroll
        for (int fm = 0; fm < 2; ++fm)
#pragma unroll
            for (int fn = 0; fn < 4; ++fn)
                acc[fm][fn] = __builtin_amdgcn_mfma_f32_16x16x32_bf16(
                    af[fm], bf[fn], acc[fm][fn], 0, 0, 0);
    };

    loadT(0);
    writeT(0);
    __syncthreads();

    for (int kt = 0; kt < NKT; ++kt) {
        int cb = kt & 1;
        if (kt + 1 < NKT) loadT(kt + 1);
        computeT(cb);
        if (kt + 1 < NKT) writeT(cb ^ 1);
        __syncthreads();
    }

    // epilogue: store raw xW as bf16
#pragma unroll
    for (int fn = 0; fn < 4; ++fn) {
        int o = wn * 64 + fn * 16 + l15;
#pragma unroll
        for (int fm = 0; fm < 2; ++fm) {
#pragma unroll
            for (int r = 0; r < 4; ++r) {
                int t = t0 + wm * 32 + fm * 16 + ksl * 4 + r;
                logits[((size_t)b * T_ + t) * OUT_ + o] = f2bf(acc[fm][fn][r]);
            }
        }
    }
}

// ---------------------------------------------------------------------------
// Kernel 2: merge — recompute seg start/cnt in-block, then
// out[b][o][s] = mean(logits over run) + bias (0 if empty), transposed store.
// Block = (b, 64-segment stripe); 256 thr; grid 512. ~34 KB LDS -> 4 blk/CU.
// ---------------------------------------------------------------------------
__global__ __launch_bounds__(256) void merge_kernel(
    const ushort* __restrict__ logits, const int* __restrict__ seg,
    const float* __restrict__ bias, float* __restrict__ out)
{
    int blk = blockIdx.x;
    int b   = blk >> 3;
    int s0  = (blk & 7) * 64;
    int tid = threadIdx.x;

    __shared__ int   sstart[64];
    __shared__ int   scnt[64];
    __shared__ float tile[OUT_][65];   // [o][sl], padded

    if (tid < 64) { sstart[tid] = T_; scnt[tid] = 0; }
    __syncthreads();
#pragma unroll
    for (int p = 0; p < 2; ++p) {
        int t = tid + p * 256;
        int li = seg[b * T_ + t] - s0;
        if (li >= 0 && li < 64) {
            atomicMin(&sstart[li], t);
            atomicAdd(&scnt[li], 1);
        }
    }
    __syncthreads();

    // compute means: consecutive lanes -> consecutive o (coalesced reads)
#pragma unroll
    for (int it = 0; it < 32; ++it) {
        int idx = tid + it * 256;     // 0..8191
        int sl  = idx >> 7;           // 0..63 (uniform per wave)
        int o   = idx & 127;
        int c   = scnt[sl];
        float v = 0.f;
        if (c > 0) {
            int st = sstart[sl];
            const ushort* src = logits + ((size_t)b * T_ + st) * OUT_ + o;
            float sum = 0.f;
            for (int i = 0; i < c; ++i) sum += bf2f(src[(size_t)i * OUT_]);
            v = sum / (float)c + bias[o];
        }
        tile[o][sl] = v;
    }
    __syncthreads();

    // transposed store: consecutive lanes -> consecutive s (coalesced writes)
#pragma unroll
    for (int p = 0; p < 32; ++p) {
        int o  = (tid >> 6) + p * 4;
        int sl = tid & 63;
        out[((size_t)b * OUT_ + o) * T_ + s0 + sl] = tile[o][sl];
    }
}

// ---------------------------------------------------------------------------
extern "C" void kernel_launch(void* const* d_in, const int* in_sizes, int n_in,
                              void* d_out, int out_size, void* d_ws, size_t ws_size,
                              hipStream_t stream) {
    const float* hs   = (const float*)d_in[0];   // (B, S, H)
    const float* W    = (const float*)d_in[1];   // (H, OUT)
    const float* bias = (const float*)d_in[2];   // (OUT,)
    const int*   seg  = (const int*)d_in[3];     // (B, T)
    float* out = (float*)d_out;                  // (B, OUT, T)

    // ws layout: logits bf16 (8.4 MB) | Wt bf16 (256 KB)
    ushort* logits = (ushort*)d_ws;
    ushort* Wt     = logits + (size_t)B_ * T_ * OUT_;

    wt_kernel<<<dim3(H_ / 64, OUT_ / 64), 256, 0, stream>>>(W, Wt);
    gemm_kernel<<<B_ * (T_ / BM), 256, 0, stream>>>(hs, Wt, logits);
    merge_kernel<<<B_ * (T_ / 64), 256, 0, stream>>>(logits, seg, bias, out);
}

// Round 9
// 57.305 us; speedup vs baseline: 1.9598x; 1.0009x over previous
//
#include <hip/hip_runtime.h>
#include <hip/hip_bf16.h>

#define B_    64
#define S_    513
#define T_    512
#define H_    1024
#define OUT_  128

#define BM 64
#define BN 128
#define BK 32
#define NKT (H_ / BK)   // 32

typedef __attribute__((ext_vector_type(8))) short short8_t;
typedef __attribute__((ext_vector_type(4))) float f32x4;

__device__ inline ushort f2bf(float f) {
    union { float f; unsigned u; } x; x.f = f;
    unsigned r = x.u + 0x7fffu + ((x.u >> 16) & 1u);   // RNE
    return (ushort)(r >> 16);
}
__device__ inline float bf2f(ushort u) {
    union { unsigned u; float f; } x; x.u = (unsigned)u << 16; return x.f;
}

// ---------------------------------------------------------------------------
// Kernel 0: Wt[o][k] = bf16(W[k][o])  (256 KB, stays L2-resident)
// ---------------------------------------------------------------------------
__global__ __launch_bounds__(256) void wt_kernel(
    const float* __restrict__ W, ushort* __restrict__ Wt)
{
    __shared__ ushort tile[64][65];
    int k0 = blockIdx.x * 64, o0 = blockIdx.y * 64;
    int tid = threadIdx.x;
#pragma unroll
    for (int p = 0; p < 16; ++p) {
        int idx = tid + p * 256;
        int r = idx >> 6, c = idx & 63;
        tile[r][c] = f2bf(W[(size_t)(k0 + r) * OUT_ + o0 + c]);
    }
    __syncthreads();
#pragma unroll
    for (int p = 0; p < 16; ++p) {
        int idx = tid + p * 256;
        int c = idx >> 6, r = idx & 63;
        Wt[(size_t)(o0 + c) * H_ + k0 + r] = tile[r][c];
    }
}

// ---------------------------------------------------------------------------
// Kernel 1: logits(bf16) = bf16(x) @ bf16(W) via MFMA 16x16x32 (no bias; raw
// xW stored). Round-2 proven body: 64x128 tile, BK=32, 256 thr = 4 waves
// (2x2), wave tile 32x64, XOR-swizzled LDS, double-buffered, 1 barrier/iter.
// 25.6 KB LDS -> 6 blocks/CU. grid 512.
// ---------------------------------------------------------------------------
__global__ __launch_bounds__(256) void gemm_kernel(
    const float* __restrict__ hs, const ushort* __restrict__ Wt,
    ushort* __restrict__ logits)
{
    __shared__ __align__(16) ushort As[2][BM * BK];
    __shared__ __align__(16) ushort Bs[2][BN * BK];

    int blk = blockIdx.x;
    int b   = blk >> 3;
    int t0  = (blk & 7) * BM;
    int tid = threadIdx.x;
    int lane = tid & 63;
    int wv = tid >> 6;
    int wm = wv & 1, wn = wv >> 1;
    int l15 = lane & 15, ksl = lane >> 4;

    int rowA = tid >> 2;          // 0..63
    int cblk = tid & 3;           // 16B chunk within BK
    int rowB1 = rowA + 64;

    const float*  aptr  = hs + ((size_t)(b * S_ + 1 + t0) + rowA) * H_ + cblk * 8;
    const ushort* bptr0 = Wt + (size_t)rowA  * H_ + cblk * 8;
    const ushort* bptr1 = Wt + (size_t)rowB1 * H_ + cblk * 8;

    auto swz = [](int row, int blkc) {
        return row * BK + ((blkc ^ ((row >> 1) & 3)) << 3);
    };
    int wAo  = swz(rowA, cblk);
    int wB0o = swz(rowA, cblk);
    int wB1o = swz(rowB1, cblk);

    int rAo[2], rBo[4];
#pragma unroll
    for (int fm = 0; fm < 2; ++fm) {
        int row = wm * 32 + fm * 16 + l15;
        rAo[fm] = swz(row, ksl);
    }
#pragma unroll
    for (int fn = 0; fn < 4; ++fn) {
        int row = wn * 64 + fn * 16 + l15;
        rBo[fn] = swz(row, ksl);
    }

    f32x4 acc[2][4];
#pragma unroll
    for (int fm = 0; fm < 2; ++fm)
#pragma unroll
        for (int fn = 0; fn < 4; ++fn) acc[fm][fn] = (f32x4){0.f, 0.f, 0.f, 0.f};

    float4 ra0, ra1;
    int4 rb0, rb1;

    auto loadT = [&](int kt) {
        const float* ap = aptr + kt * BK;
        ra0 = *reinterpret_cast<const float4*>(ap);
        ra1 = *reinterpret_cast<const float4*>(ap + 4);
        rb0 = *reinterpret_cast<const int4*>(bptr0 + kt * BK);
        rb1 = *reinterpret_cast<const int4*>(bptr1 + kt * BK);
    };
    auto writeT = [&](int nb) {
        union { ushort u[8]; int4 i; } pa;
        pa.u[0] = f2bf(ra0.x); pa.u[1] = f2bf(ra0.y);
        pa.u[2] = f2bf(ra0.z); pa.u[3] = f2bf(ra0.w);
        pa.u[4] = f2bf(ra1.x); pa.u[5] = f2bf(ra1.y);
        pa.u[6] = f2bf(ra1.z); pa.u[7] = f2bf(ra1.w);
        *reinterpret_cast<int4*>(&As[nb][wAo])  = pa.i;
        *reinterpret_cast<int4*>(&Bs[nb][wB0o]) = rb0;
        *reinterpret_cast<int4*>(&Bs[nb][wB1o]) = rb1;
    };
    auto computeT = [&](int cb) {
        short8_t af[2], bf[4];
#pragma unroll
        for (int fm = 0; fm < 2; ++fm)
            af[fm] = *reinterpret_cast<const short8_t*>(&As[cb][rAo[fm]]);
#pragma unroll
        for (int fn = 0; fn < 4; ++fn)
            bf[fn] = *reinterpret_cast<const short8_t*>(&Bs[cb][rBo[fn]]);
#pragma unroll
        for (int fm = 0; fm < 2; ++fm)
#pragma unroll
            for (int fn = 0; fn < 4; ++fn)
                acc[fm][fn] = __builtin_amdgcn_mfma_f32_16x16x32_bf16(
                    af[fm], bf[fn], acc[fm][fn], 0, 0, 0);
    };

    loadT(0);
    writeT(0);
    __syncthreads();

    for (int kt = 0; kt < NKT; ++kt) {
        int cb = kt & 1;
        if (kt + 1 < NKT) loadT(kt + 1);
        computeT(cb);
        if (kt + 1 < NKT) writeT(cb ^ 1);
        __syncthreads();
    }

    // epilogue: store raw xW as bf16
#pragma unroll
    for (int fn = 0; fn < 4; ++fn) {
        int o = wn * 64 + fn * 16 + l15;
#pragma unroll
        for (int fm = 0; fm < 2; ++fm) {
#pragma unroll
            for (int r = 0; r < 4; ++r) {
                int t = t0 + wm * 32 + fm * 16 + ksl * 4 + r;
                logits[((size_t)b * T_ + t) * OUT_ + o] = f2bf(acc[fm][fn][r]);
            }
        }
    }
}

// ---------------------------------------------------------------------------
// Kernel 2: merge — recompute seg start/cnt in-block, then
// out[b][o][s] = mean(logits over run) + bias (0 if empty), transposed store.
// Block = (b, 64-segment stripe); 256 thr; grid 512. ~34 KB LDS -> 4 blk/CU.
// ---------------------------------------------------------------------------
__global__ __launch_bounds__(256) void merge_kernel(
    const ushort* __restrict__ logits, const int* __restrict__ seg,
    const float* __restrict__ bias, float* __restrict__ out)
{
    int blk = blockIdx.x;
    int b   = blk >> 3;
    int s0  = (blk & 7) * 64;
    int tid = threadIdx.x;

    __shared__ int   sstart[64];
    __shared__ int   scnt[64];
    __shared__ float tile[OUT_][65];   // [o][sl], padded

    if (tid < 64) { sstart[tid] = T_; scnt[tid] = 0; }
    __syncthreads();
#pragma unroll
    for (int p = 0; p < 2; ++p) {
        int t = tid + p * 256;
        int li = seg[b * T_ + t] - s0;
        if (li >= 0 && li < 64) {
            atomicMin(&sstart[li], t);
            atomicAdd(&scnt[li], 1);
        }
    }
    __syncthreads();

    // compute means: consecutive lanes -> consecutive o (coalesced reads)
#pragma unroll
    for (int it = 0; it < 32; ++it) {
        int idx = tid + it * 256;     // 0..8191
        int sl  = idx >> 7;           // 0..63 (uniform per wave)
        int o   = idx & 127;
        int c   = scnt[sl];
        float v = 0.f;
        if (c > 0) {
            int st = sstart[sl];
            const ushort* src = logits + ((size_t)b * T_ + st) * OUT_ + o;
            float sum = 0.f;
            for (int i = 0; i < c; ++i) sum += bf2f(src[(size_t)i * OUT_]);
            v = sum / (float)c + bias[o];
        }
        tile[o][sl] = v;
    }
    __syncthreads();

    // transposed store: consecutive lanes -> consecutive s (coalesced writes)
#pragma unroll
    for (int p = 0; p < 32; ++p) {
        int o  = (tid >> 6) + p * 4;
        int sl = tid & 63;
        out[((size_t)b * OUT_ + o) * T_ + s0 + sl] = tile[o][sl];
    }
}

// ---------------------------------------------------------------------------
extern "C" void kernel_launch(void* const* d_in, const int* in_sizes, int n_in,
                              void* d_out, int out_size, void* d_ws, size_t ws_size,
                              hipStream_t stream) {
    const float* hs   = (const float*)d_in[0];   // (B, S, H)
    const float* W    = (const float*)d_in[1];   // (H, OUT)
    const float* bias = (const float*)d_in[2];   // (OUT,)
    const int*   seg  = (const int*)d_in[3];     // (B, T)
    float* out = (float*)d_out;                  // (B, OUT, T)

    // ws layout: logits bf16 (8.4 MB) | Wt bf16 (256 KB)
    ushort* logits = (ushort*)d_ws;
    ushort* Wt     = logits + (size_t)B_ * T_ * OUT_;

    wt_kernel<<<dim3(H_ / 64, OUT_ / 64), 256, 0, stream>>>(W, Wt);
    gemm_kernel<<<B_ * (T_ / BM), 256, 0, stream>>>(hs, Wt, logits);
    merge_kernel<<<B_ * (T_ / 64), 256, 0, stream>>>(logits, seg, bias, out);
}